// Round 3
// baseline (419.309 us; speedup 1.0000x reference)
//
#include <hip/hip_runtime.h>
#include <hip/hip_bf16.h>

// features [1024,1024] f32, W [1024,1024] f32 (nn.Linear: P = F @ W^T + b),
// b [1024] f32, prototypes [32768,1024] f32 (rows L2-normalized).
// Outputs: activations [1024,32768] f32, best_idx [1024] (float-coded ints).

typedef __attribute__((ext_vector_type(8))) short short8;   // 8 x bf16
typedef __attribute__((ext_vector_type(4))) float floatx4;  // MFMA C/D frag

__device__ __forceinline__ unsigned short f2bf(float f) {
  unsigned int u = __float_as_uint(f);
  u += 0x7fffu + ((u >> 16) & 1u);  // RNE
  return (unsigned short)(u >> 16);
}
__device__ __forceinline__ float bf2f(unsigned short h) {
  return __uint_as_float(((unsigned int)h) << 16);
}

// ---------------- f32 -> bf16 convert, 8 elems/thread (protos) -------------
__global__ __launch_bounds__(256) void cvt_f32_bf16(
    const float* __restrict__ src, unsigned short* __restrict__ dst, int n8) {
  int i = blockIdx.x * blockDim.x + threadIdx.x;
  if (i >= n8) return;
  const float4* s4 = (const float4*)src;
  float4 a = s4[2 * i];
  float4 b = s4[2 * i + 1];
  short8 o;
  o[0] = (short)f2bf(a.x); o[1] = (short)f2bf(a.y);
  o[2] = (short)f2bf(a.z); o[3] = (short)f2bf(a.w);
  o[4] = (short)f2bf(b.x); o[5] = (short)f2bf(b.y);
  o[6] = (short)f2bf(b.z); o[7] = (short)f2bf(b.w);
  ((short8*)dst)[i] = o;
}

// ---------------- f32 -> 3-way bf16 split (h + m + l ~= x to 2^-27) --------
__global__ __launch_bounds__(256) void cvt_split3(
    const float* __restrict__ src, unsigned short* __restrict__ H,
    unsigned short* __restrict__ Md, unsigned short* __restrict__ L, int n4) {
  int i = blockIdx.x * blockDim.x + threadIdx.x;
  if (i >= n4) return;
  float4 x = ((const float4*)src)[i];
  ushort4 h, m, l;
  float v, r;
  v = x.x; h.x = f2bf(v); r = v - bf2f(h.x); m.x = f2bf(r); l.x = f2bf(r - bf2f(m.x));
  v = x.y; h.y = f2bf(v); r = v - bf2f(h.y); m.y = f2bf(r); l.y = f2bf(r - bf2f(m.y));
  v = x.z; h.z = f2bf(v); r = v - bf2f(h.z); m.z = f2bf(r); l.z = f2bf(r - bf2f(m.z));
  v = x.w; h.w = f2bf(v); r = v - bf2f(h.w); m.w = f2bf(r); l.w = f2bf(r - bf2f(m.w));
  ((ushort4*)H)[i] = h; ((ushort4*)Md)[i] = m; ((ushort4*)L)[i] = l;
}

// ======== 256x256-tile bf16 NT GEMM: C[M,N] = A[M,K] @ B[N,K]^T ============
// 8 waves (2M x 4N), BK=64, 128 KiB LDS double-buffer, swizzled reads,
// counted vmcnt(4), 3 barrier-pairs per K-tile (merged p3/p4), setprio
// around MFMA. Epilogue additionally emits per-(row, n-block) softmax
// partials (m = max z, l = sum exp(z-m), z = 10*sim) to ml[].
// Fixed shape: M=1024, N=32768, K=1024.

#define BARRIER() asm volatile("s_barrier" ::: "memory")
#define WAITLGKM()                                        \
  do {                                                    \
    asm volatile("s_waitcnt lgkmcnt(0)" ::: "memory");    \
    __builtin_amdgcn_sched_barrier(0);                    \
  } while (0)
#define WAITVM4() asm volatile("s_waitcnt vmcnt(4)" ::: "memory")

#define STAGE(OP, SLOT, H, KT)                                                 \
  do {                                                                         \
    const unsigned short* _s0 = (OP ? pB0 : pA0) + (H)*131072 + (KT)*64;       \
    const unsigned short* _s1 = (OP ? pB1 : pA1) + (H)*131072 + (KT)*64;       \
    __builtin_amdgcn_global_load_lds(                                          \
        (const __attribute__((address_space(1))) void*)_s0,                    \
        (__attribute__((address_space(3))) void*)(&lds[SLOT][OP][(H)*8192 + w * 512]), \
        16, 0, 0);                                                             \
    __builtin_amdgcn_global_load_lds(                                          \
        (const __attribute__((address_space(1))) void*)_s1,                    \
        (__attribute__((address_space(3))) void*)(&lds[SLOT][OP][(H)*8192 + 4096 + w * 512]), \
        16, 0, 0);                                                             \
  } while (0)

#define READ4(dst, base, off, rowadd)                                          \
  _Pragma("unroll") for (int q = 0; q < 4; q++)                                \
      dst[q] = *(const short8*)((base) + (off) + ((rowadd) + q) * 2048);

#define MFMA16(AB, BB, MBASE)                                                  \
  do {                                                                         \
    __builtin_amdgcn_sched_barrier(0);                                         \
    __builtin_amdgcn_s_setprio(1);                                             \
    _Pragma("unroll") for (int mf = 0; mf < 4; mf++)                           \
        _Pragma("unroll") for (int nf = 0; nf < 4; nf++)                       \
            acc[(MBASE) + mf][nf] = __builtin_amdgcn_mfma_f32_16x16x32_bf16(   \
                AB[mf], BB[nf], acc[(MBASE) + mf][nf], 0, 0, 0);               \
    __builtin_amdgcn_s_setprio(0);                                             \
    __builtin_amdgcn_sched_barrier(0);                                         \
  } while (0)

__global__ __launch_bounds__(512, 2) void gemm_nt_bf16_256(
    const unsigned short* __restrict__ A, const unsigned short* __restrict__ B,
    float* __restrict__ C, float* __restrict__ ml, int M, int N, int K) {
  // [slot][op: 0=A 1=B][256 rows x 64 cols bf16] = 128 KiB
  __shared__ unsigned short lds[2][2][16384];
  const int tid = threadIdx.x;
  const int w = tid >> 6, lane = tid & 63;
  const int wr = w >> 2, wc = w & 3;
  const int fr = lane & 15, koff8 = lane >> 4;

  // XCD-aware bijective tile remap: XCD c owns n-panels [16c,16c+16), each
  // with all 4 m-tiles consecutive -> B working set per XCD stays L2/L3-warm.
  const int bid = blockIdx.x;
  const int c8 = bid & 7, u = bid >> 3;
  const int nb = c8 * 16 + (u >> 2);       // n-block index 0..127
  const long tn = (long)nb * 256;
  const long tm = (long)(u & 3) * 256;

  // Staging source offsets (linear LDS dest, inverse-swizzled global source):
  // LDS chunk idx holds logical (row r = idx>>3, chunk c = (idx&7) ^ (r&7)).
  const int idx0 = w * 64 + lane;
  const int idx1 = 512 + idx0;
  const int rh0 = idx0 >> 3, sc0 = (idx0 & 7) ^ (rh0 & 7);
  const int rh1 = idx1 >> 3, sc1 = (idx1 & 7) ^ (rh1 & 7);
  const unsigned short* pA0 = A + (tm + rh0) * 1024 + sc0 * 8;
  const unsigned short* pA1 = A + (tm + rh1) * 1024 + sc1 * 8;
  const unsigned short* pB0 = B + (tn + rh0) * 1024 + sc0 * 8;
  const unsigned short* pB1 = B + (tn + rh1) * 1024 + sc1 * 8;

  // Swizzled read offsets (bytes within one 32 KiB operand region).
  const int rA = wr * 128 + fr;
  const int rB = wc * 64 + fr;
  const int offA0 = rA * 128 + ((koff8 ^ (rA & 7)) << 4);
  const int offA1 = rA * 128 + (((koff8 ^ 4) ^ (rA & 7)) << 4);
  const int offB0 = rB * 128 + ((koff8 ^ (rB & 7)) << 4);
  const int offB1 = rB * 128 + (((koff8 ^ 4) ^ (rB & 7)) << 4);

  const char* ldsc = (const char*)&lds[0][0][0];
#define LDSA(s) (ldsc + (s)*65536)
#define LDSB(s) (ldsc + (s)*65536 + 32768)

  floatx4 acc[8][4];
#pragma unroll
  for (int i = 0; i < 8; i++)
#pragma unroll
    for (int j = 0; j < 4; j++) acc[i][j] = (floatx4){0.f, 0.f, 0.f, 0.f};

  short8 a0[4], a1[4], a2[4], b0[4], b1[4];

  // Prologue: T0 fully -> slot0; T1.A -> slot1. (12 issued, keep 4.)
  STAGE(0, 0, 0, 0); STAGE(0, 0, 1, 0); STAGE(1, 0, 0, 0); STAGE(1, 0, 1, 0);
  STAGE(0, 1, 0, 1); STAGE(0, 1, 1, 1);
  WAITVM4();
  BARRIER();

#pragma unroll 1
  for (int i = 0; i < 8; i++) {
    const int t1 = 2 * i + 1;
    const int t2 = (2 * i + 2) & 15;
    const int t3 = (2 * i + 3) & 15;

    // ---- K-tile 2i (slot 0): all slot0 ds_reads confined to q1/q2 ----
    // q1
    READ4(a0, LDSA(0), offA0, 0);   // A frags 0-3, ksub0
    READ4(a1, LDSA(0), offA0, 4);   // A frags 4-7, ksub0
    READ4(b0, LDSB(0), offB0, 0);   // B frags 0-3, ksub0
    STAGE(1, 1, 0, t1);             // T(2i+1).Bh0 -> slot1
    BARRIER(); WAITLGKM();
    MFMA16(a0, b0, 0);
    BARRIER();
    // q2 (two MFMA clusters; all slot0 reads complete by q2's final barrier)
    READ4(a0, LDSA(0), offA1, 0);   // A frags 0-3, ksub1 (a0 dead after q1)
    READ4(a2, LDSA(0), offA1, 4);   // A frags 4-7, ksub1
    READ4(b1, LDSB(0), offB1, 0);   // B frags 0-3, ksub1
    STAGE(1, 1, 1, t1);             // T(2i+1).Bh1 -> slot1
    BARRIER(); WAITLGKM();
    MFMA16(a1, b0, 4);
    MFMA16(a0, b1, 0);
    BARRIER();
    // q3 (slot0 fully read -> stage both A halves, drain slot1 deps)
    STAGE(0, 0, 0, t2);             // T(2i+2).Ah0 -> slot0
    STAGE(0, 0, 1, t2);             // T(2i+2).Ah1 -> slot0
    WAITVM4();                      // drains T(2i+1) A+B; keeps q3's 4 loads
    BARRIER();
    MFMA16(a2, b1, 4);
    BARRIER();

    // ---- K-tile 2i+1 (slot 1) ----
    // q4
    READ4(a0, LDSA(1), offA0, 0);
    READ4(a1, LDSA(1), offA0, 4);
    READ4(b0, LDSB(1), offB0, 0);
    STAGE(1, 0, 0, t2);             // T(2i+2).Bh0 -> slot0
    BARRIER(); WAITLGKM();
    MFMA16(a0, b0, 0);
    BARRIER();
    // q5
    READ4(a0, LDSA(1), offA1, 0);
    READ4(a2, LDSA(1), offA1, 4);
    READ4(b1, LDSB(1), offB1, 0);
    STAGE(1, 0, 1, t2);             // T(2i+2).Bh1 -> slot0
    BARRIER(); WAITLGKM();
    MFMA16(a1, b0, 4);
    MFMA16(a0, b1, 0);
    BARRIER();
    // q6
    STAGE(0, 1, 0, t3);             // T(2i+3).Ah0 -> slot1
    STAGE(0, 1, 1, t3);             // T(2i+3).Ah1 -> slot1
    WAITVM4();                      // drains T(2i+2) A+B; keeps q6's 4 loads
    BARRIER();
    MFMA16(a2, b1, 4);
    BARRIER();
  }

  // ---- epilogue 1: per-(row, n-block) softmax partials -------------------
  // z = 10*sim. Per (mf,r): 4 distinct rows (by hi=lane>>4); row's 4 nf
  // values in-lane, 16 cols across fr. shfl_xor 1/2/4/8 stays in fr-group.
  // Overlay float2 mlx[2][128][4] (8 KiB) on slot0-A region: last slot0
  // writes were drained by q6's vmcnt; in-flight strays target slot1 only.
  {
    float2* mlx = (float2*)&lds[0][0][0];
    const int hi = lane >> 4;
#pragma unroll
    for (int mf = 0; mf < 8; mf++)
#pragma unroll
      for (int r = 0; r < 4; r++) {
        float z0 = acc[mf][0][r] * 10.f, z1 = acc[mf][1][r] * 10.f;
        float z2 = acc[mf][2][r] * 10.f, z3 = acc[mf][3][r] * 10.f;
        float mz = fmaxf(fmaxf(z0, z1), fmaxf(z2, z3));
#pragma unroll
        for (int off = 1; off < 16; off <<= 1) mz = fmaxf(mz, __shfl_xor(mz, off));
        float ls = __expf(z0 - mz) + __expf(z1 - mz) +
                   __expf(z2 - mz) + __expf(z3 - mz);
#pragma unroll
        for (int off = 1; off < 16; off <<= 1) ls += __shfl_xor(ls, off);
        if (fr == 0) mlx[(wr * 128 + mf * 16 + hi * 4 + r) * 4 + wc] =
            make_float2(mz, ls);
      }
    __syncthreads();
    if (tid < 256) {
      const int wrr = tid >> 7, row = tid & 127;
      float2 q0 = mlx[(wrr * 128 + row) * 4 + 0];
      float2 q1 = mlx[(wrr * 128 + row) * 4 + 1];
      float2 q2 = mlx[(wrr * 128 + row) * 4 + 2];
      float2 q3 = mlx[(wrr * 128 + row) * 4 + 3];
      float Mb = fmaxf(fmaxf(q0.x, q1.x), fmaxf(q2.x, q3.x));
      float Lb = q0.y * __expf(q0.x - Mb) + q1.y * __expf(q1.x - Mb) +
                 q2.y * __expf(q2.x - Mb) + q3.y * __expf(q3.x - Mb);
      ((float2*)ml)[(long)nb * 1024 + (tm + wrr * 128 + row)] =
          make_float2(Mb, Lb);
    }
  }

  // ---- epilogue 2: C write (layout col=lane&15, row=(lane>>4)*4+r) -------
  const long crow = tm + wr * 128 + ((lane >> 4) * 4);
  const long ccol = tn + wc * 64 + fr;
#pragma unroll
  for (int mf = 0; mf < 8; mf++)
#pragma unroll
    for (int nf = 0; nf < 4; nf++)
#pragma unroll
      for (int r = 0; r < 4; r++)
        C[(crow + mf * 16 + r) * (long)N + ccol + nf * 16] = acc[mf][nf][r];
#undef LDSA
#undef LDSB
}

// ---------------- split-bf16 NT GEMM (6 products), split-K partials --------
// Cpart[z] = partial over K-range [z*K/gz, (z+1)*K/gz). 64x64 tile, BK=32.
__global__ __launch_bounds__(256) void gemm_split6_nt(
    const unsigned short* __restrict__ Ah, const unsigned short* __restrict__ Am,
    const unsigned short* __restrict__ Al, const unsigned short* __restrict__ Bh,
    const unsigned short* __restrict__ Bm, const unsigned short* __restrict__ Bl,
    float* __restrict__ Cpart, int M, int N, int K) {
  __shared__ unsigned short sA[3][64 * 32];
  __shared__ unsigned short sB[3][64 * 32];
  const int tid  = threadIdx.x;
  const int wave = tid >> 6;
  const int lane = tid & 63;
  const long tm = (long)blockIdx.y * 64;
  const long tn = (long)blockIdx.x * 64;
  const int wm = (wave & 1) * 32;
  const int wn = (wave >> 1) * 32;
  const int ksize = K / gridDim.z;
  const int kbase = blockIdx.z * ksize;
  float* C = Cpart + (size_t)blockIdx.z * M * N;

  floatx4 accH[2][2], accL[2][2];
#pragma unroll
  for (int i = 0; i < 2; i++)
#pragma unroll
    for (int j = 0; j < 2; j++) {
      accH[i][j] = (floatx4){0.f, 0.f, 0.f, 0.f};
      accL[i][j] = (floatx4){0.f, 0.f, 0.f, 0.f};
    }

  const int rstage = tid >> 2;
  const int cstage = (tid & 3) * 8;
  const long aoff = (tm + rstage) * (long)K + cstage;
  const long boff = (tn + rstage) * (long)K + cstage;
  const unsigned short* Asrc[3] = {Ah + aoff, Am + aoff, Al + aoff};
  const unsigned short* Bsrc[3] = {Bh + boff, Bm + boff, Bl + boff};

  for (int k0 = kbase; k0 < kbase + ksize; k0 += 32) {
#pragma unroll
    for (int p = 0; p < 3; p++) {
      __builtin_amdgcn_global_load_lds(
          (const __attribute__((address_space(1))) void*)(Asrc[p] + k0),
          (__attribute__((address_space(3))) void*)(sA[p] + wave * 512), 16, 0, 0);
      __builtin_amdgcn_global_load_lds(
          (const __attribute__((address_space(1))) void*)(Bsrc[p] + k0),
          (__attribute__((address_space(3))) void*)(sB[p] + wave * 512), 16, 0, 0);
    }
    __syncthreads();

    const int fr = lane & 15;
    const int koff = (lane >> 4) * 8;
    short8 a_[3][2], b_[3][2];
#pragma unroll
    for (int p = 0; p < 3; p++)
#pragma unroll
      for (int mf = 0; mf < 2; mf++) {
        a_[p][mf] = *(const short8*)(sA[p] + (wm + mf * 16 + fr) * 32 + koff);
        b_[p][mf] = *(const short8*)(sB[p] + (wn + mf * 16 + fr) * 32 + koff);
      }
#pragma unroll
    for (int mf = 0; mf < 2; mf++)
#pragma unroll
      for (int nf = 0; nf < 2; nf++) {
        accH[mf][nf] = __builtin_amdgcn_mfma_f32_16x16x32_bf16(
            a_[0][mf], b_[0][nf], accH[mf][nf], 0, 0, 0);  // hh
        accL[mf][nf] = __builtin_amdgcn_mfma_f32_16x16x32_bf16(
            a_[0][mf], b_[1][nf], accL[mf][nf], 0, 0, 0);  // hm
        accL[mf][nf] = __builtin_amdgcn_mfma_f32_16x16x32_bf16(
            a_[1][mf], b_[0][nf], accL[mf][nf], 0, 0, 0);  // mh
        accL[mf][nf] = __builtin_amdgcn_mfma_f32_16x16x32_bf16(
            a_[0][mf], b_[2][nf], accL[mf][nf], 0, 0, 0);  // hl
        accL[mf][nf] = __builtin_amdgcn_mfma_f32_16x16x32_bf16(
            a_[2][mf], b_[0][nf], accL[mf][nf], 0, 0, 0);  // lh
        accL[mf][nf] = __builtin_amdgcn_mfma_f32_16x16x32_bf16(
            a_[1][mf], b_[1][nf], accL[mf][nf], 0, 0, 0);  // mm
      }
    __syncthreads();
  }

  const long crow = tm + wm + ((lane >> 4) * 4);
  const long ccol = tn + wn + (lane & 15);
#pragma unroll
  for (int mf = 0; mf < 2; mf++)
#pragma unroll
    for (int nf = 0; nf < 2; nf++)
#pragma unroll
      for (int r = 0; r < 4; r++)
        C[(crow + mf * 16 + r) * (long)N + ccol + nf * 16] =
            accH[mf][nf][r] + accL[mf][nf][r];
}

// ------- bias + reduce split-K partials + L2-normalize -> bf16 + f32 -------
__global__ __launch_bounds__(256) void norm_bias_rows(
    const float* __restrict__ P0, const float* __restrict__ P1, int nparts,
    const float* __restrict__ bias, unsigned short* __restrict__ Pn,
    float* __restrict__ Pn32) {
  const int b = blockIdx.x, tid = threadIdx.x;
  float4 v = ((const float4*)(P0 + (long)b * 1024))[tid];
  if (nparts == 2) {
    float4 v1 = ((const float4*)(P1 + (long)b * 1024))[tid];
    v.x += v1.x; v.y += v1.y; v.z += v1.z; v.w += v1.w;
  }
  float4 bb = ((const float4*)bias)[tid];
  v.x += bb.x; v.y += bb.y; v.z += bb.z; v.w += bb.w;
  float ss = v.x * v.x + v.y * v.y + v.z * v.z + v.w * v.w;
#pragma unroll
  for (int off = 32; off > 0; off >>= 1) ss += __shfl_down(ss, off);
  __shared__ float wred[4];
  if ((tid & 63) == 0) wred[tid >> 6] = ss;
  __syncthreads();
  float tot = wred[0] + wred[1] + wred[2] + wred[3];
  float inv = 1.0f / fmaxf(sqrtf(tot), 1e-12f);
  float4 p = make_float4(v.x * inv, v.y * inv, v.z * inv, v.w * inv);
  ((float4*)Pn32)[b * 256 + tid] = p;
  ushort4 o;
  o.x = f2bf(p.x); o.y = f2bf(p.y); o.z = f2bf(p.z); o.w = f2bf(p.w);
  ((ushort4*)Pn)[b * 256 + tid] = o;
}

// ------- softmax (single pass, GEMM-supplied partials) + exact argmax ------
// Combine 128 per-block (m,l) pairs -> Mz, L; then ONE pass over S: write
// activations + collect candidates; f64 refine for exact argmax.
__global__ __launch_bounds__(256) void softmax_argmax_refine(
    float* __restrict__ S, const float* __restrict__ Pn32,
    const float* __restrict__ protos, const float* __restrict__ ml,
    float* __restrict__ idx_out) {
  const int b = blockIdx.x, tid = threadIdx.x;
  const int wave = tid >> 6, lane = tid & 63;
  float4* row4 = (float4*)(S + (long)b * 32768);

  __shared__ float2 mlred[2];
  __shared__ int cand[64];
  __shared__ int ncand;
  if (tid == 0) ncand = 0;

  if (wave < 2) {  // tid 0..127 <-> n-block 0..127
    float2 p = ((const float2*)ml)[(long)tid * 1024 + b];
    float m = p.x, l = p.y;
#pragma unroll
    for (int off = 1; off < 64; off <<= 1) {
      float mo = __shfl_xor(m, off);
      float lo = __shfl_xor(l, off);
      float nm = fmaxf(m, mo);
      l = l * __expf(m - nm) + lo * __expf(mo - nm);
      m = nm;
    }
    if (lane == 0) mlred[wave] = make_float2(m, l);
  }
  __syncthreads();
  const float m0 = mlred[0].x, m1 = mlred[1].x;
  const float Mz = fmaxf(m0, m1);
  const float L = mlred[0].y * __expf(m0 - Mz) + mlred[1].y * __expf(m1 - Mz);
  const float invL = 1.0f / L;
  // worst-case bf16 GEMM sim error <= 2^-8 = 0.0039; margin 0.012 > 2*err
  const float thr = Mz * 0.1f - 0.012f;  // sim-scale

#pragma unroll 4
  for (int it = 0; it < 32; it++) {
    int i4 = tid + 256 * it;
    float4 v = row4[i4];
    if (fmaxf(fmaxf(v.x, v.y), fmaxf(v.z, v.w)) >= thr) {
      if (v.x >= thr) { int p = atomicAdd(&ncand, 1); if (p < 64) cand[p] = i4 * 4; }
      if (v.y >= thr) { int p = atomicAdd(&ncand, 1); if (p < 64) cand[p] = i4 * 4 + 1; }
      if (v.z >= thr) { int p = atomicAdd(&ncand, 1); if (p < 64) cand[p] = i4 * 4 + 2; }
      if (v.w >= thr) { int p = atomicAdd(&ncand, 1); if (p < 64) cand[p] = i4 * 4 + 3; }
    }
    float4 e;
    e.x = __expf(v.x * 10.f - Mz) * invL;
    e.y = __expf(v.y * 10.f - Mz) * invL;
    e.z = __expf(v.z * 10.f - Mz) * invL;
    e.w = __expf(v.w * 10.f - Mz) * invL;
    row4[i4] = e;
  }
  __syncthreads();
  int n = ncand < 64 ? ncand : 64;

  float4 pv = ((const float4*)(Pn32 + (long)b * 1024))[tid];
  __shared__ double dred[4];
  double best = -1e300;
  int besti = 0x7fffffff;
  for (int c = 0; c < n; c++) {
    int k = cand[c];
    float4 kv = ((const float4*)(protos + (long)k * 1024))[tid];
    double d = (double)pv.x * kv.x + (double)pv.y * kv.y +
               (double)pv.z * kv.z + (double)pv.w * kv.w;
#pragma unroll
    for (int off = 32; off > 0; off >>= 1) d += __shfl_down(d, off);
    if (lane == 0) dred[wave] = d;
    __syncthreads();
    if (tid == 0) {
      double tot = dred[0] + dred[1] + dred[2] + dred[3];
      if (tot > best || (tot == best && k < besti)) { best = tot; besti = k; }
    }
    __syncthreads();
  }
  if (tid == 0) idx_out[b] = (float)besti;
}

extern "C" void kernel_launch(void* const* d_in, const int* in_sizes, int n_in,
                              void* d_out, int out_size, void* d_ws, size_t ws_size,
                              hipStream_t stream) {
  const float* features = (const float*)d_in[0];
  const float* W        = (const float*)d_in[1];
  const float* bias     = (const float*)d_in[2];
  const float* protos   = (const float*)d_in[3];

  const size_t MB = 1024 * 1024;
  char* ws = (char*)d_ws;
  unsigned short* protoB = (unsigned short*)ws;              // 64 MiB
  unsigned short* Fh = (unsigned short*)(ws + 64 * MB);      // 2 MiB each
  unsigned short* Fm = (unsigned short*)(ws + 66 * MB);
  unsigned short* Fl = (unsigned short*)(ws + 68 * MB);
  unsigned short* Wh = (unsigned short*)(ws + 70 * MB);
  unsigned short* Wm = (unsigned short*)(ws + 72 * MB);
  unsigned short* Wl = (unsigned short*)(ws + 74 * MB);
  float*          P0 = (float*)(ws + 76 * MB);               // 4 MiB
  float*          P1 = (float*)(ws + 80 * MB);               // 4 MiB (split-K)
  // F/W splits dead after projection GEMM -> reuse their space:
  unsigned short* Pn   = (unsigned short*)(ws + 64 * MB);    // 2 MiB
  float*          Pn32 = (float*)(ws + 66 * MB);             // 4 MiB
  // P0/P1 dead after norm_bias_rows -> big GEMM's ml partials reuse P0 space:
  float*          mlb  = (float*)(ws + 76 * MB);             // 1 MiB [128][1024][2]

  // split-K=2 needs 84 MiB of ws; fall back to 1 otherwise (ws_size is
  // constant across calls -> same work every launch, graph-safe)
  const int ksplit = (ws_size >= 84 * MB) ? 2 : 1;

  float* S = (float*)d_out;                      // [1024,32768]
  float* idx_out = S + (size_t)1024 * 32768;     // [1024] float-coded

  cvt_f32_bf16<<<16384, 256, 0, stream>>>(protos, protoB, 32768 * 1024 / 8);
  cvt_split3<<<1024, 256, 0, stream>>>(features, Fh, Fm, Fl, 1024 * 1024 / 4);
  cvt_split3<<<1024, 256, 0, stream>>>(W, Wh, Wm, Wl, 1024 * 1024 / 4);
  gemm_split6_nt<<<dim3(16, 16, ksplit), 256, 0, stream>>>(
      Fh, Fm, Fl, Wh, Wm, Wl, P0, 1024, 1024, 1024);
  norm_bias_rows<<<1024, 256, 0, stream>>>(P0, P1, ksplit, bias, Pn, Pn32);
  gemm_nt_bf16_256<<<512, 512, 0, stream>>>(Pn, protoB, S, mlb, 1024, 32768, 1024);
  softmax_argmax_refine<<<1024, 256, 0, stream>>>(S, Pn32, protos, mlb, idx_out);
}

// Round 4
// 410.306 us; speedup vs baseline: 1.0219x; 1.0219x over previous
//
#include <hip/hip_runtime.h>
#include <hip/hip_bf16.h>

// features [1024,1024] f32, W [1024,1024] f32 (nn.Linear: P = F @ W^T + b),
// b [1024] f32, prototypes [32768,1024] f32 (rows L2-normalized).
// Outputs: activations [1024,32768] f32, best_idx [1024] (float-coded ints).

typedef __attribute__((ext_vector_type(8))) short short8;   // 8 x bf16
typedef __attribute__((ext_vector_type(4))) float floatx4;  // MFMA C/D frag

__device__ __forceinline__ unsigned short f2bf(float f) {
  unsigned int u = __float_as_uint(f);
  u += 0x7fffu + ((u >> 16) & 1u);  // RNE
  return (unsigned short)(u >> 16);
}
__device__ __forceinline__ float bf2f(unsigned short h) {
  return __uint_as_float(((unsigned int)h) << 16);
}

// ------ fused prep: protos f32->bf16 + features/W 3-way bf16 split ---------
// blocks [0,16384): protos (8 elems/thread); [16384,17408): features split3
// (4 elems/thread); [17408,18432): W split3. Disjoint outputs, no sync needed.
__global__ __launch_bounds__(256) void prep_convert(
    const float* __restrict__ protos, unsigned short* __restrict__ protoB,
    const float* __restrict__ features, unsigned short* __restrict__ Fh,
    unsigned short* __restrict__ Fm, unsigned short* __restrict__ Fl,
    const float* __restrict__ W, unsigned short* __restrict__ Wh,
    unsigned short* __restrict__ Wm, unsigned short* __restrict__ Wl) {
  const int blk = blockIdx.x;
  if (blk < 16384) {
    int i = blk * 256 + threadIdx.x;            // < 32768*1024/8
    const float4* s4 = (const float4*)protos;
    float4 a = s4[2 * i];
    float4 b = s4[2 * i + 1];
    short8 o;
    o[0] = (short)f2bf(a.x); o[1] = (short)f2bf(a.y);
    o[2] = (short)f2bf(a.z); o[3] = (short)f2bf(a.w);
    o[4] = (short)f2bf(b.x); o[5] = (short)f2bf(b.y);
    o[6] = (short)f2bf(b.z); o[7] = (short)f2bf(b.w);
    ((short8*)protoB)[i] = o;
    return;
  }
  const float* src; unsigned short *H, *Md, *L; int i;
  if (blk < 17408) {
    src = features; H = Fh; Md = Fm; L = Fl;
    i = (blk - 16384) * 256 + threadIdx.x;      // < 1024*1024/4
  } else {
    src = W; H = Wh; Md = Wm; L = Wl;
    i = (blk - 17408) * 256 + threadIdx.x;
  }
  float4 x = ((const float4*)src)[i];
  ushort4 h, m, l;
  float v, r;
  v = x.x; h.x = f2bf(v); r = v - bf2f(h.x); m.x = f2bf(r); l.x = f2bf(r - bf2f(m.x));
  v = x.y; h.y = f2bf(v); r = v - bf2f(h.y); m.y = f2bf(r); l.y = f2bf(r - bf2f(m.y));
  v = x.z; h.z = f2bf(v); r = v - bf2f(h.z); m.z = f2bf(r); l.z = f2bf(r - bf2f(m.z));
  v = x.w; h.w = f2bf(v); r = v - bf2f(h.w); m.w = f2bf(r); l.w = f2bf(r - bf2f(m.w));
  ((ushort4*)H)[i] = h; ((ushort4*)Md)[i] = m; ((ushort4*)L)[i] = l;
}

// ======== 256x256-tile bf16 NT GEMM: C[M,N] = A[M,K] @ B[N,K]^T ============
// 8 waves (2M x 4N), BK=64, 128 KiB LDS double-buffer, swizzled reads,
// counted vmcnt(4) at phases 4/8 only, 8-phase schedule (round-1 verified:
// 84.8 us; do NOT merge phases — m196-style coarsening cost +21 us).
// Epilogue emits per-(row, n-block) softmax partials (m=max z, l=sum exp)
// to ml[]. Fixed shape: M=1024, N=32768, K=1024.

#define BARRIER() asm volatile("s_barrier" ::: "memory")
#define WAITLGKM()                                        \
  do {                                                    \
    asm volatile("s_waitcnt lgkmcnt(0)" ::: "memory");    \
    __builtin_amdgcn_sched_barrier(0);                    \
  } while (0)
#define WAITVM4() asm volatile("s_waitcnt vmcnt(4)" ::: "memory")

#define STAGE(OP, SLOT, H, KT)                                                 \
  do {                                                                         \
    const unsigned short* _s0 = (OP ? pB0 : pA0) + (H)*131072 + (KT)*64;       \
    const unsigned short* _s1 = (OP ? pB1 : pA1) + (H)*131072 + (KT)*64;       \
    __builtin_amdgcn_global_load_lds(                                          \
        (const __attribute__((address_space(1))) void*)_s0,                    \
        (__attribute__((address_space(3))) void*)(&lds[SLOT][OP][(H)*8192 + w * 512]), \
        16, 0, 0);                                                             \
    __builtin_amdgcn_global_load_lds(                                          \
        (const __attribute__((address_space(1))) void*)_s1,                    \
        (__attribute__((address_space(3))) void*)(&lds[SLOT][OP][(H)*8192 + 4096 + w * 512]), \
        16, 0, 0);                                                             \
  } while (0)

#define READ4(dst, base, off, rowadd)                                          \
  _Pragma("unroll") for (int q = 0; q < 4; q++)                                \
      dst[q] = *(const short8*)((base) + (off) + ((rowadd) + q) * 2048);

#define MFMA16(AB, BB, MBASE)                                                  \
  do {                                                                         \
    __builtin_amdgcn_sched_barrier(0);                                         \
    __builtin_amdgcn_s_setprio(1);                                             \
    _Pragma("unroll") for (int mf = 0; mf < 4; mf++)                           \
        _Pragma("unroll") for (int nf = 0; nf < 4; nf++)                       \
            acc[(MBASE) + mf][nf] = __builtin_amdgcn_mfma_f32_16x16x32_bf16(   \
                AB[mf], BB[nf], acc[(MBASE) + mf][nf], 0, 0, 0);               \
    __builtin_amdgcn_s_setprio(0);                                             \
    __builtin_amdgcn_sched_barrier(0);                                         \
  } while (0)

__global__ __launch_bounds__(512, 2) void gemm_nt_bf16_256(
    const unsigned short* __restrict__ A, const unsigned short* __restrict__ B,
    float* __restrict__ C, float* __restrict__ ml, int M, int N, int K) {
  // [slot][op: 0=A 1=B][256 rows x 64 cols bf16] = 128 KiB
  __shared__ unsigned short lds[2][2][16384];
  const int tid = threadIdx.x;
  const int w = tid >> 6, lane = tid & 63;
  const int wr = w >> 2, wc = w & 3;
  const int fr = lane & 15, koff8 = lane >> 4;

  // XCD-aware bijective tile remap: XCD c owns n-panels [16c,16c+16), each
  // with all 4 m-tiles consecutive -> B working set per XCD stays L2-warm.
  const int bid = blockIdx.x;
  const int c8 = bid & 7, u = bid >> 3;
  const int nb = c8 * 16 + (u >> 2);       // n-block index 0..127
  const long tn = (long)nb * 256;
  const long tm = (long)(u & 3) * 256;

  // Staging source offsets (linear LDS dest, inverse-swizzled global source):
  // LDS chunk idx holds logical (row r = idx>>3, chunk c = (idx&7) ^ (r&7)).
  const int idx0 = w * 64 + lane;
  const int idx1 = 512 + idx0;
  const int rh0 = idx0 >> 3, sc0 = (idx0 & 7) ^ (rh0 & 7);
  const int rh1 = idx1 >> 3, sc1 = (idx1 & 7) ^ (rh1 & 7);
  const unsigned short* pA0 = A + (tm + rh0) * 1024 + sc0 * 8;
  const unsigned short* pA1 = A + (tm + rh1) * 1024 + sc1 * 8;
  const unsigned short* pB0 = B + (tn + rh0) * 1024 + sc0 * 8;
  const unsigned short* pB1 = B + (tn + rh1) * 1024 + sc1 * 8;

  // Swizzled read offsets (bytes within one 32 KiB operand region).
  const int rA = wr * 128 + fr;
  const int rB = wc * 64 + fr;
  const int offA0 = rA * 128 + ((koff8 ^ (rA & 7)) << 4);
  const int offA1 = rA * 128 + (((koff8 ^ 4) ^ (rA & 7)) << 4);
  const int offB0 = rB * 128 + ((koff8 ^ (rB & 7)) << 4);
  const int offB1 = rB * 128 + (((koff8 ^ 4) ^ (rB & 7)) << 4);

  const char* ldsc = (const char*)&lds[0][0][0];
#define LDSA(s) (ldsc + (s)*65536)
#define LDSB(s) (ldsc + (s)*65536 + 32768)

  floatx4 acc[8][4];
#pragma unroll
  for (int i = 0; i < 8; i++)
#pragma unroll
    for (int j = 0; j < 4; j++) acc[i][j] = (floatx4){0.f, 0.f, 0.f, 0.f};

  short8 a0[4], a1[4], a2[4], b0[4], b1[4];

  // Prologue: T0 fully -> slot0; T1.A -> slot1. (12 issued, keep 4.)
  STAGE(0, 0, 0, 0); STAGE(0, 0, 1, 0); STAGE(1, 0, 0, 0); STAGE(1, 0, 1, 0);
  STAGE(0, 1, 0, 1); STAGE(0, 1, 1, 1);
  WAITVM4();
  BARRIER();

#pragma unroll 1
  for (int i = 0; i < 8; i++) {
    const int t1 = 2 * i + 1;
    const int t2 = (2 * i + 2) & 15;
    const int t3 = (2 * i + 3) & 15;

    // ---- K-tile 2i (slot 0): all slot0 ds_reads confined to p1/p2 ----
    // p1
    READ4(a0, LDSA(0), offA0, 0);   // A frags 0-3, ksub0
    READ4(a1, LDSA(0), offA0, 4);   // A frags 4-7, ksub0
    READ4(b0, LDSB(0), offB0, 0);   // B frags 0-3, ksub0
    STAGE(1, 1, 0, t1);             // T(2i+1).Bh0 -> slot1
    BARRIER(); WAITLGKM();
    MFMA16(a0, b0, 0);
    BARRIER();
    // p2
    READ4(a0, LDSA(0), offA1, 0);   // A frags 0-3, ksub1 (a0 dead after p1)
    READ4(a2, LDSA(0), offA1, 4);   // A frags 4-7, ksub1
    READ4(b1, LDSB(0), offB1, 0);   // B frags 0-3, ksub1
    STAGE(1, 1, 1, t1);             // T(2i+1).Bh1 -> slot1
    BARRIER(); WAITLGKM();
    MFMA16(a1, b0, 4);
    BARRIER();
    // p3 (slot0 fully read -> safe to begin overwriting slot0)
    STAGE(0, 0, 0, t2);             // T(2i+2).Ah0 -> slot0
    BARRIER();
    MFMA16(a0, b1, 0);
    BARRIER();
    // p4
    STAGE(0, 0, 1, t2);             // T(2i+2).Ah1 -> slot0
    WAITVM4();                      // slot1 complete for p5 (keep p3/p4 in flight)
    BARRIER();
    MFMA16(a2, b1, 4);
    BARRIER();

    // ---- K-tile 2i+1 (slot 1) ----
    // p5
    READ4(a0, LDSA(1), offA0, 0);
    READ4(a1, LDSA(1), offA0, 4);
    READ4(b0, LDSB(1), offB0, 0);
    STAGE(1, 0, 0, t2);             // T(2i+2).Bh0 -> slot0
    BARRIER(); WAITLGKM();
    MFMA16(a0, b0, 0);
    BARRIER();
    // p6
    READ4(a0, LDSA(1), offA1, 0);
    READ4(a2, LDSA(1), offA1, 4);
    READ4(b1, LDSB(1), offB1, 0);
    STAGE(1, 0, 1, t2);             // T(2i+2).Bh1 -> slot0
    BARRIER(); WAITLGKM();
    MFMA16(a1, b0, 4);
    BARRIER();
    // p7 (slot1 fully read)
    STAGE(0, 1, 0, t3);             // T(2i+3).Ah0 -> slot1
    BARRIER();
    MFMA16(a0, b1, 0);
    BARRIER();
    // p8
    STAGE(0, 1, 1, t3);             // T(2i+3).Ah1 -> slot1
    WAITVM4();                      // slot0 complete for next iter p1
    BARRIER();
    MFMA16(a2, b1, 4);
    BARRIER();
  }

  // ---- epilogue 1: per-(row, n-block) softmax partials -------------------
  // z = 10*sim. Per (mf,r): 4 distinct rows (by hi=lane>>4); row's 4 nf
  // values in-lane, 16 cols across fr. shfl_xor 1/2/4/8 stays in fr-group.
  // Overlay float2 mlx[2][128][4] (8 KiB) on slot0-A region: final p8 vmcnt
  // drained all slot0 stores; last in-flight stores target slot1 only.
  {
    float2* mlx = (float2*)&lds[0][0][0];
    const int hi = lane >> 4;
#pragma unroll
    for (int mf = 0; mf < 8; mf++)
#pragma unroll
      for (int r = 0; r < 4; r++) {
        float z0 = acc[mf][0][r] * 10.f, z1 = acc[mf][1][r] * 10.f;
        float z2 = acc[mf][2][r] * 10.f, z3 = acc[mf][3][r] * 10.f;
        float mz = fmaxf(fmaxf(z0, z1), fmaxf(z2, z3));
#pragma unroll
        for (int off = 1; off < 16; off <<= 1) mz = fmaxf(mz, __shfl_xor(mz, off));
        float ls = __expf(z0 - mz) + __expf(z1 - mz) +
                   __expf(z2 - mz) + __expf(z3 - mz);
#pragma unroll
        for (int off = 1; off < 16; off <<= 1) ls += __shfl_xor(ls, off);
        if (fr == 0) mlx[(wr * 128 + mf * 16 + hi * 4 + r) * 4 + wc] =
            make_float2(mz, ls);
      }
    __syncthreads();
    if (tid < 256) {
      const int wrr = tid >> 7, row = tid & 127;
      float2 q0 = mlx[(wrr * 128 + row) * 4 + 0];
      float2 q1 = mlx[(wrr * 128 + row) * 4 + 1];
      float2 q2 = mlx[(wrr * 128 + row) * 4 + 2];
      float2 q3 = mlx[(wrr * 128 + row) * 4 + 3];
      float Mb = fmaxf(fmaxf(q0.x, q1.x), fmaxf(q2.x, q3.x));
      float Lb = q0.y * __expf(q0.x - Mb) + q1.y * __expf(q1.x - Mb) +
                 q2.y * __expf(q2.x - Mb) + q3.y * __expf(q3.x - Mb);
      ((float2*)ml)[(long)nb * 1024 + (tm + wrr * 128 + row)] =
          make_float2(Mb, Lb);
    }
  }

  // ---- epilogue 2: C write (layout col=lane&15, row=(lane>>4)*4+r) -------
  const long crow = tm + wr * 128 + ((lane >> 4) * 4);
  const long ccol = tn + wc * 64 + fr;
#pragma unroll
  for (int mf = 0; mf < 8; mf++)
#pragma unroll
    for (int nf = 0; nf < 4; nf++)
#pragma unroll
      for (int r = 0; r < 4; r++)
        C[(crow + mf * 16 + r) * (long)N + ccol + nf * 16] = acc[mf][nf][r];
#undef LDSA
#undef LDSB
}

// ---------------- split-bf16 NT GEMM (6 products), split-K partials --------
// Cpart[z] = partial over K-range [z*K/gz, (z+1)*K/gz). 64x64 tile, BK=32.
__global__ __launch_bounds__(256) void gemm_split6_nt(
    const unsigned short* __restrict__ Ah, const unsigned short* __restrict__ Am,
    const unsigned short* __restrict__ Al, const unsigned short* __restrict__ Bh,
    const unsigned short* __restrict__ Bm, const unsigned short* __restrict__ Bl,
    float* __restrict__ Cpart, int M, int N, int K) {
  __shared__ unsigned short sA[3][64 * 32];
  __shared__ unsigned short sB[3][64 * 32];
  const int tid  = threadIdx.x;
  const int wave = tid >> 6;
  const int lane = tid & 63;
  const long tm = (long)blockIdx.y * 64;
  const long tn = (long)blockIdx.x * 64;
  const int wm = (wave & 1) * 32;
  const int wn = (wave >> 1) * 32;
  const int ksize = K / gridDim.z;
  const int kbase = blockIdx.z * ksize;
  float* C = Cpart + (size_t)blockIdx.z * M * N;

  floatx4 accH[2][2], accL[2][2];
#pragma unroll
  for (int i = 0; i < 2; i++)
#pragma unroll
    for (int j = 0; j < 2; j++) {
      accH[i][j] = (floatx4){0.f, 0.f, 0.f, 0.f};
      accL[i][j] = (floatx4){0.f, 0.f, 0.f, 0.f};
    }

  const int rstage = tid >> 2;
  const int cstage = (tid & 3) * 8;
  const long aoff = (tm + rstage) * (long)K + cstage;
  const long boff = (tn + rstage) * (long)K + cstage;
  const unsigned short* Asrc[3] = {Ah + aoff, Am + aoff, Al + aoff};
  const unsigned short* Bsrc[3] = {Bh + boff, Bm + boff, Bl + boff};

  for (int k0 = kbase; k0 < kbase + ksize; k0 += 32) {
#pragma unroll
    for (int p = 0; p < 3; p++) {
      __builtin_amdgcn_global_load_lds(
          (const __attribute__((address_space(1))) void*)(Asrc[p] + k0),
          (__attribute__((address_space(3))) void*)(sA[p] + wave * 512), 16, 0, 0);
      __builtin_amdgcn_global_load_lds(
          (const __attribute__((address_space(1))) void*)(Bsrc[p] + k0),
          (__attribute__((address_space(3))) void*)(sB[p] + wave * 512), 16, 0, 0);
    }
    __syncthreads();

    const int fr = lane & 15;
    const int koff = (lane >> 4) * 8;
    short8 a_[3][2], b_[3][2];
#pragma unroll
    for (int p = 0; p < 3; p++)
#pragma unroll
      for (int mf = 0; mf < 2; mf++) {
        a_[p][mf] = *(const short8*)(sA[p] + (wm + mf * 16 + fr) * 32 + koff);
        b_[p][mf] = *(const short8*)(sB[p] + (wn + mf * 16 + fr) * 32 + koff);
      }
#pragma unroll
    for (int mf = 0; mf < 2; mf++)
#pragma unroll
      for (int nf = 0; nf < 2; nf++) {
        accH[mf][nf] = __builtin_amdgcn_mfma_f32_16x16x32_bf16(
            a_[0][mf], b_[0][nf], accH[mf][nf], 0, 0, 0);  // hh
        accL[mf][nf] = __builtin_amdgcn_mfma_f32_16x16x32_bf16(
            a_[0][mf], b_[1][nf], accL[mf][nf], 0, 0, 0);  // hm
        accL[mf][nf] = __builtin_amdgcn_mfma_f32_16x16x32_bf16(
            a_[1][mf], b_[0][nf], accL[mf][nf], 0, 0, 0);  // mh
        accL[mf][nf] = __builtin_amdgcn_mfma_f32_16x16x32_bf16(
            a_[0][mf], b_[2][nf], accL[mf][nf], 0, 0, 0);  // hl
        accL[mf][nf] = __builtin_amdgcn_mfma_f32_16x16x32_bf16(
            a_[2][mf], b_[0][nf], accL[mf][nf], 0, 0, 0);  // lh
        accL[mf][nf] = __builtin_amdgcn_mfma_f32_16x16x32_bf16(
            a_[1][mf], b_[1][nf], accL[mf][nf], 0, 0, 0);  // mm
      }
    __syncthreads();
  }

  const long crow = tm + wm + ((lane >> 4) * 4);
  const long ccol = tn + wn + (lane & 15);
#pragma unroll
  for (int mf = 0; mf < 2; mf++)
#pragma unroll
    for (int nf = 0; nf < 2; nf++)
#pragma unroll
      for (int r = 0; r < 4; r++)
        C[(crow + mf * 16 + r) * (long)N + ccol + nf * 16] =
            accH[mf][nf][r] + accL[mf][nf][r];
}

// ------- bias + reduce split-K partials + L2-normalize -> bf16 + f32 -------
__global__ __launch_bounds__(256) void norm_bias_rows(
    const float* __restrict__ P0, const float* __restrict__ P1, int nparts,
    const float* __restrict__ bias, unsigned short* __restrict__ Pn,
    float* __restrict__ Pn32) {
  const int b = blockIdx.x, tid = threadIdx.x;
  float4 v = ((const float4*)(P0 + (long)b * 1024))[tid];
  if (nparts == 2) {
    float4 v1 = ((const float4*)(P1 + (long)b * 1024))[tid];
    v.x += v1.x; v.y += v1.y; v.z += v1.z; v.w += v1.w;
  }
  float4 bb = ((const float4*)bias)[tid];
  v.x += bb.x; v.y += bb.y; v.z += bb.z; v.w += bb.w;
  float ss = v.x * v.x + v.y * v.y + v.z * v.z + v.w * v.w;
#pragma unroll
  for (int off = 32; off > 0; off >>= 1) ss += __shfl_down(ss, off);
  __shared__ float wred[4];
  if ((tid & 63) == 0) wred[tid >> 6] = ss;
  __syncthreads();
  float tot = wred[0] + wred[1] + wred[2] + wred[3];
  float inv = 1.0f / fmaxf(sqrtf(tot), 1e-12f);
  float4 p = make_float4(v.x * inv, v.y * inv, v.z * inv, v.w * inv);
  ((float4*)Pn32)[b * 256 + tid] = p;
  ushort4 o;
  o.x = f2bf(p.x); o.y = f2bf(p.y); o.z = f2bf(p.z); o.w = f2bf(p.w);
  ((ushort4*)Pn)[b * 256 + tid] = o;
}

// ------- softmax (single pass, GEMM-supplied partials) + exact argmax ------
// Combine 128 per-block (m,l) pairs -> Mz, L; then ONE pass over S: write
// activations + collect candidates; f64 refine for exact argmax.
__global__ __launch_bounds__(256) void softmax_argmax_refine(
    float* __restrict__ S, const float* __restrict__ Pn32,
    const float* __restrict__ protos, const float* __restrict__ ml,
    float* __restrict__ idx_out) {
  const int b = blockIdx.x, tid = threadIdx.x;
  const int wave = tid >> 6, lane = tid & 63;
  float4* row4 = (float4*)(S + (long)b * 32768);

  __shared__ float2 mlred[2];
  __shared__ int cand[64];
  __shared__ int ncand;
  if (tid == 0) ncand = 0;

  if (wave < 2) {  // tid 0..127 <-> n-block 0..127
    float2 p = ((const float2*)ml)[(long)tid * 1024 + b];
    float m = p.x, l = p.y;
#pragma unroll
    for (int off = 1; off < 64; off <<= 1) {
      float mo = __shfl_xor(m, off);
      float lo = __shfl_xor(l, off);
      float nm = fmaxf(m, mo);
      l = l * __expf(m - nm) + lo * __expf(mo - nm);
      m = nm;
    }
    if (lane == 0) mlred[wave] = make_float2(m, l);
  }
  __syncthreads();
  const float m0 = mlred[0].x, m1 = mlred[1].x;
  const float Mz = fmaxf(m0, m1);
  const float L = mlred[0].y * __expf(m0 - Mz) + mlred[1].y * __expf(m1 - Mz);
  const float invL = 1.0f / L;
  // worst-case bf16 GEMM sim error <= 2^-8 = 0.0039; margin 0.012 > 2*err
  const float thr = Mz * 0.1f - 0.012f;  // sim-scale

#pragma unroll 4
  for (int it = 0; it < 32; it++) {
    int i4 = tid + 256 * it;
    float4 v = row4[i4];
    if (fmaxf(fmaxf(v.x, v.y), fmaxf(v.z, v.w)) >= thr) {
      if (v.x >= thr) { int p = atomicAdd(&ncand, 1); if (p < 64) cand[p] = i4 * 4; }
      if (v.y >= thr) { int p = atomicAdd(&ncand, 1); if (p < 64) cand[p] = i4 * 4 + 1; }
      if (v.z >= thr) { int p = atomicAdd(&ncand, 1); if (p < 64) cand[p] = i4 * 4 + 2; }
      if (v.w >= thr) { int p = atomicAdd(&ncand, 1); if (p < 64) cand[p] = i4 * 4 + 3; }
    }
    float4 e;
    e.x = __expf(v.x * 10.f - Mz) * invL;
    e.y = __expf(v.y * 10.f - Mz) * invL;
    e.z = __expf(v.z * 10.f - Mz) * invL;
    e.w = __expf(v.w * 10.f - Mz) * invL;
    row4[i4] = e;
  }
  __syncthreads();
  int n = ncand < 64 ? ncand : 64;

  float4 pv = ((const float4*)(Pn32 + (long)b * 1024))[tid];
  __shared__ double dred[4];
  double best = -1e300;
  int besti = 0x7fffffff;
  for (int c = 0; c < n; c++) {
    int k = cand[c];
    float4 kv = ((const float4*)(protos + (long)k * 1024))[tid];
    double d = (double)pv.x * kv.x + (double)pv.y * kv.y +
               (double)pv.z * kv.z + (double)pv.w * kv.w;
#pragma unroll
    for (int off = 32; off > 0; off >>= 1) d += __shfl_down(d, off);
    if (lane == 0) dred[wave] = d;
    __syncthreads();
    if (tid == 0) {
      double tot = dred[0] + dred[1] + dred[2] + dred[3];
      if (tot > best || (tot == best && k < besti)) { best = tot; besti = k; }
    }
    __syncthreads();
  }
  if (tid == 0) idx_out[b] = (float)besti;
}

extern "C" void kernel_launch(void* const* d_in, const int* in_sizes, int n_in,
                              void* d_out, int out_size, void* d_ws, size_t ws_size,
                              hipStream_t stream) {
  const float* features = (const float*)d_in[0];
  const float* W        = (const float*)d_in[1];
  const float* bias     = (const float*)d_in[2];
  const float* protos   = (const float*)d_in[3];

  const size_t MB = 1024 * 1024;
  char* ws = (char*)d_ws;
  unsigned short* protoB = (unsigned short*)ws;              // 64 MiB
  unsigned short* Fh = (unsigned short*)(ws + 64 * MB);      // 2 MiB each
  unsigned short* Fm = (unsigned short*)(ws + 66 * MB);
  unsigned short* Fl = (unsigned short*)(ws + 68 * MB);
  unsigned short* Wh = (unsigned short*)(ws + 70 * MB);
  unsigned short* Wm = (unsigned short*)(ws + 72 * MB);
  unsigned short* Wl = (unsigned short*)(ws + 74 * MB);
  float*          P0 = (float*)(ws + 76 * MB);               // 4 MiB
  float*          P1 = (float*)(ws + 80 * MB);               // 4 MiB (split-K)
  // F/W splits dead after projection GEMM -> reuse their space:
  unsigned short* Pn   = (unsigned short*)(ws + 64 * MB);    // 2 MiB
  float*          Pn32 = (float*)(ws + 66 * MB);             // 4 MiB
  // P0/P1 dead after norm_bias_rows -> big GEMM's ml partials reuse P0 space:
  float*          mlb  = (float*)(ws + 76 * MB);             // 1 MiB [128][1024][2]

  // split-K=2 needs 84 MiB of ws; fall back to 1 otherwise (ws_size is
  // constant across calls -> same work every launch, graph-safe)
  const int ksplit = (ws_size >= 84 * MB) ? 2 : 1;

  float* S = (float*)d_out;                      // [1024,32768]
  float* idx_out = S + (size_t)1024 * 32768;     // [1024] float-coded

  prep_convert<<<18432, 256, 0, stream>>>(protos, protoB, features, Fh, Fm, Fl,
                                          W, Wh, Wm, Wl);
  gemm_split6_nt<<<dim3(16, 16, ksplit), 256, 0, stream>>>(
      Fh, Fm, Fl, Wh, Wm, Wl, P0, 1024, 1024, 1024);
  norm_bias_rows<<<1024, 256, 0, stream>>>(P0, P1, ksplit, bias, Pn, Pn32);
  gemm_nt_bf16_256<<<512, 512, 0, stream>>>(Pn, protoB, S, mlb, 1024, 32768, 1024);
  softmax_argmax_refine<<<1024, 256, 0, stream>>>(S, Pn32, protos, mlb, idx_out);
}

// Round 5
// 400.159 us; speedup vs baseline: 1.0479x; 1.0254x over previous
//
#include <hip/hip_runtime.h>
#include <hip/hip_bf16.h>

// features [1024,1024] f32, W [1024,1024] f32 (nn.Linear: P = F @ W^T + b),
// b [1024] f32, prototypes [32768,1024] f32 (rows L2-normalized).
// Outputs: activations [1024,32768] f32, best_idx [1024] (float-coded ints).

typedef __attribute__((ext_vector_type(8))) short short8;   // 8 x bf16
typedef __attribute__((ext_vector_type(4))) float floatx4;  // MFMA C/D frag

__device__ __forceinline__ unsigned short f2bf(float f) {
  unsigned int u = __float_as_uint(f);
  u += 0x7fffu + ((u >> 16) & 1u);  // RNE
  return (unsigned short)(u >> 16);
}
__device__ __forceinline__ float bf2f(unsigned short h) {
  return __uint_as_float(((unsigned int)h) << 16);
}

// ------ fused prep: protos f32->bf16 + features/W 3-way bf16 split ---------
__global__ __launch_bounds__(256) void prep_convert(
    const float* __restrict__ protos, unsigned short* __restrict__ protoB,
    const float* __restrict__ features, unsigned short* __restrict__ Fh,
    unsigned short* __restrict__ Fm, unsigned short* __restrict__ Fl,
    const float* __restrict__ W, unsigned short* __restrict__ Wh,
    unsigned short* __restrict__ Wm, unsigned short* __restrict__ Wl) {
  const int blk = blockIdx.x;
  if (blk < 16384) {
    int i = blk * 256 + threadIdx.x;            // < 32768*1024/8
    const float4* s4 = (const float4*)protos;
    float4 a = s4[2 * i];
    float4 b = s4[2 * i + 1];
    short8 o;
    o[0] = (short)f2bf(a.x); o[1] = (short)f2bf(a.y);
    o[2] = (short)f2bf(a.z); o[3] = (short)f2bf(a.w);
    o[4] = (short)f2bf(b.x); o[5] = (short)f2bf(b.y);
    o[6] = (short)f2bf(b.z); o[7] = (short)f2bf(b.w);
    ((short8*)protoB)[i] = o;
    return;
  }
  const float* src; unsigned short *H, *Md, *L; int i;
  if (blk < 17408) {
    src = features; H = Fh; Md = Fm; L = Fl;
    i = (blk - 16384) * 256 + threadIdx.x;      // < 1024*1024/4
  } else {
    src = W; H = Wh; Md = Wm; L = Wl;
    i = (blk - 17408) * 256 + threadIdx.x;
  }
  float4 x = ((const float4*)src)[i];
  ushort4 h, m, l;
  float v, r;
  v = x.x; h.x = f2bf(v); r = v - bf2f(h.x); m.x = f2bf(r); l.x = f2bf(r - bf2f(m.x));
  v = x.y; h.y = f2bf(v); r = v - bf2f(h.y); m.y = f2bf(r); l.y = f2bf(r - bf2f(m.y));
  v = x.z; h.z = f2bf(v); r = v - bf2f(h.z); m.z = f2bf(r); l.z = f2bf(r - bf2f(m.z));
  v = x.w; h.w = f2bf(v); r = v - bf2f(h.w); m.w = f2bf(r); l.w = f2bf(r - bf2f(m.w));
  ((ushort4*)H)[i] = h; ((ushort4*)Md)[i] = m; ((ushort4*)L)[i] = l;
}

// ======== 256x256-tile bf16 NT GEMM: C[M,N] = A[M,K] @ B[N,K]^T ============
// 8 waves (2M x 4N), BK=64, 128 KiB LDS double-buffer, swizzled reads,
// counted vmcnt(4) at phases 4/8 only, 8-phase schedule (round-1 verified
// 84.8 us). C is stored BF16 into the BACK HALF of each 128 KiB output row
// (bytes [row*131072+65536, +65536)) — softmax forgives the quantization
// (T=0.1 saturates; bf16-input error ~1e-3 already passes at absmax 1e-6).
// NO reduction epilogue here: round-4 measured the shfl/exp ml-epilogue at
// +19 us (MfmaUtil dilution 32.5->26.4 matched 104/84.8 exactly).
// Fixed shape: M=1024, N=32768, K=1024.

#define BARRIER() asm volatile("s_barrier" ::: "memory")
#define WAITLGKM()                                        \
  do {                                                    \
    asm volatile("s_waitcnt lgkmcnt(0)" ::: "memory");    \
    __builtin_amdgcn_sched_barrier(0);                    \
  } while (0)
#define WAITVM4() asm volatile("s_waitcnt vmcnt(4)" ::: "memory")

#define STAGE(OP, SLOT, H, KT)                                                 \
  do {                                                                         \
    const unsigned short* _s0 = (OP ? pB0 : pA0) + (H)*131072 + (KT)*64;       \
    const unsigned short* _s1 = (OP ? pB1 : pA1) + (H)*131072 + (KT)*64;       \
    __builtin_amdgcn_global_load_lds(                                          \
        (const __attribute__((address_space(1))) void*)_s0,                    \
        (__attribute__((address_space(3))) void*)(&lds[SLOT][OP][(H)*8192 + w * 512]), \
        16, 0, 0);                                                             \
    __builtin_amdgcn_global_load_lds(                                          \
        (const __attribute__((address_space(1))) void*)_s1,                    \
        (__attribute__((address_space(3))) void*)(&lds[SLOT][OP][(H)*8192 + 4096 + w * 512]), \
        16, 0, 0);                                                             \
  } while (0)

#define READ4(dst, base, off, rowadd)                                          \
  _Pragma("unroll") for (int q = 0; q < 4; q++)                                \
      dst[q] = *(const short8*)((base) + (off) + ((rowadd) + q) * 2048);

#define MFMA16(AB, BB, MBASE)                                                  \
  do {                                                                         \
    __builtin_amdgcn_sched_barrier(0);                                         \
    __builtin_amdgcn_s_setprio(1);                                             \
    _Pragma("unroll") for (int mf = 0; mf < 4; mf++)                           \
        _Pragma("unroll") for (int nf = 0; nf < 4; nf++)                       \
            acc[(MBASE) + mf][nf] = __builtin_amdgcn_mfma_f32_16x16x32_bf16(   \
                AB[mf], BB[nf], acc[(MBASE) + mf][nf], 0, 0, 0);               \
    __builtin_amdgcn_s_setprio(0);                                             \
    __builtin_amdgcn_sched_barrier(0);                                         \
  } while (0)

__global__ __launch_bounds__(512, 2) void gemm_nt_bf16_256(
    const unsigned short* __restrict__ A, const unsigned short* __restrict__ B,
    unsigned short* __restrict__ Cb, int M, int N, int K) {
  // [slot][op: 0=A 1=B][256 rows x 64 cols bf16] = 128 KiB
  __shared__ unsigned short lds[2][2][16384];
  const int tid = threadIdx.x;
  const int w = tid >> 6, lane = tid & 63;
  const int wr = w >> 2, wc = w & 3;
  const int fr = lane & 15, koff8 = lane >> 4;

  // XCD-aware bijective tile remap: XCD c owns n-panels [16c,16c+16).
  const int bid = blockIdx.x;
  const int c8 = bid & 7, u = bid >> 3;
  const int nb = c8 * 16 + (u >> 2);       // n-block index 0..127
  const long tn = (long)nb * 256;
  const long tm = (long)(u & 3) * 256;

  // Staging source offsets (linear LDS dest, inverse-swizzled global source).
  const int idx0 = w * 64 + lane;
  const int idx1 = 512 + idx0;
  const int rh0 = idx0 >> 3, sc0 = (idx0 & 7) ^ (rh0 & 7);
  const int rh1 = idx1 >> 3, sc1 = (idx1 & 7) ^ (rh1 & 7);
  const unsigned short* pA0 = A + (tm + rh0) * 1024 + sc0 * 8;
  const unsigned short* pA1 = A + (tm + rh1) * 1024 + sc1 * 8;
  const unsigned short* pB0 = B + (tn + rh0) * 1024 + sc0 * 8;
  const unsigned short* pB1 = B + (tn + rh1) * 1024 + sc1 * 8;

  // Swizzled read offsets (bytes within one 32 KiB operand region).
  const int rA = wr * 128 + fr;
  const int rB = wc * 64 + fr;
  const int offA0 = rA * 128 + ((koff8 ^ (rA & 7)) << 4);
  const int offA1 = rA * 128 + (((koff8 ^ 4) ^ (rA & 7)) << 4);
  const int offB0 = rB * 128 + ((koff8 ^ (rB & 7)) << 4);
  const int offB1 = rB * 128 + (((koff8 ^ 4) ^ (rB & 7)) << 4);

  const char* ldsc = (const char*)&lds[0][0][0];
#define LDSA(s) (ldsc + (s)*65536)
#define LDSB(s) (ldsc + (s)*65536 + 32768)

  floatx4 acc[8][4];
#pragma unroll
  for (int i = 0; i < 8; i++)
#pragma unroll
    for (int j = 0; j < 4; j++) acc[i][j] = (floatx4){0.f, 0.f, 0.f, 0.f};

  short8 a0[4], a1[4], a2[4], b0[4], b1[4];

  // Prologue: T0 fully -> slot0; T1.A -> slot1. (12 issued, keep 4.)
  STAGE(0, 0, 0, 0); STAGE(0, 0, 1, 0); STAGE(1, 0, 0, 0); STAGE(1, 0, 1, 0);
  STAGE(0, 1, 0, 1); STAGE(0, 1, 1, 1);
  WAITVM4();
  BARRIER();

#pragma unroll 1
  for (int i = 0; i < 8; i++) {
    const int t1 = 2 * i + 1;
    const int t2 = (2 * i + 2) & 15;
    const int t3 = (2 * i + 3) & 15;

    // ---- K-tile 2i (slot 0) ----
    // p1
    READ4(a0, LDSA(0), offA0, 0);
    READ4(a1, LDSA(0), offA0, 4);
    READ4(b0, LDSB(0), offB0, 0);
    STAGE(1, 1, 0, t1);
    BARRIER(); WAITLGKM();
    MFMA16(a0, b0, 0);
    BARRIER();
    // p2
    READ4(a0, LDSA(0), offA1, 0);
    READ4(a2, LDSA(0), offA1, 4);
    READ4(b1, LDSB(0), offB1, 0);
    STAGE(1, 1, 1, t1);
    BARRIER(); WAITLGKM();
    MFMA16(a1, b0, 4);
    BARRIER();
    // p3
    STAGE(0, 0, 0, t2);
    BARRIER();
    MFMA16(a0, b1, 0);
    BARRIER();
    // p4
    STAGE(0, 0, 1, t2);
    WAITVM4();
    BARRIER();
    MFMA16(a2, b1, 4);
    BARRIER();

    // ---- K-tile 2i+1 (slot 1) ----
    // p5
    READ4(a0, LDSA(1), offA0, 0);
    READ4(a1, LDSA(1), offA0, 4);
    READ4(b0, LDSB(1), offB0, 0);
    STAGE(1, 0, 0, t2);
    BARRIER(); WAITLGKM();
    MFMA16(a0, b0, 0);
    BARRIER();
    // p6
    READ4(a0, LDSA(1), offA1, 0);
    READ4(a2, LDSA(1), offA1, 4);
    READ4(b1, LDSB(1), offB1, 0);
    STAGE(1, 0, 1, t2);
    BARRIER(); WAITLGKM();
    MFMA16(a1, b0, 4);
    BARRIER();
    // p7
    STAGE(0, 1, 0, t3);
    BARRIER();
    MFMA16(a0, b1, 0);
    BARRIER();
    // p8
    STAGE(0, 1, 1, t3);
    WAITVM4();
    BARRIER();
    MFMA16(a2, b1, 4);
    BARRIER();
  }

  // Epilogue: bf16 C to back half of each 128 KiB output row.
  // ushort row stride = 2N; back-half base = N.
  const long crow = tm + wr * 128 + ((lane >> 4) * 4);
  const long ccol = tn + wc * 64 + fr;
  const long rs2 = 2 * (long)N;
#pragma unroll
  for (int mf = 0; mf < 8; mf++)
#pragma unroll
    for (int nf = 0; nf < 4; nf++)
#pragma unroll
      for (int r = 0; r < 4; r++)
        Cb[(crow + mf * 16 + r) * rs2 + N + ccol + nf * 16] =
            f2bf(acc[mf][nf][r]);
#undef LDSA
#undef LDSB
}

// ---------------- split-bf16 NT GEMM (6 products), split-K partials --------
// Partial z in [0,2) -> Cpart + z*M*N; z in [2,4) -> Cpart2 + (z-2)*M*N.
__global__ __launch_bounds__(256) void gemm_split6_nt(
    const unsigned short* __restrict__ Ah, const unsigned short* __restrict__ Am,
    const unsigned short* __restrict__ Al, const unsigned short* __restrict__ Bh,
    const unsigned short* __restrict__ Bm, const unsigned short* __restrict__ Bl,
    float* __restrict__ Cpart, float* __restrict__ Cpart2, int M, int N, int K) {
  __shared__ unsigned short sA[3][64 * 32];
  __shared__ unsigned short sB[3][64 * 32];
  const int tid  = threadIdx.x;
  const int wave = tid >> 6;
  const int lane = tid & 63;
  const long tm = (long)blockIdx.y * 64;
  const long tn = (long)blockIdx.x * 64;
  const int wm = (wave & 1) * 32;
  const int wn = (wave >> 1) * 32;
  const int ksize = K / gridDim.z;
  const int kbase = blockIdx.z * ksize;
  float* C = (blockIdx.z < 2) ? (Cpart + (size_t)blockIdx.z * M * N)
                              : (Cpart2 + (size_t)(blockIdx.z - 2) * M * N);

  floatx4 accH[2][2], accL[2][2];
#pragma unroll
  for (int i = 0; i < 2; i++)
#pragma unroll
    for (int j = 0; j < 2; j++) {
      accH[i][j] = (floatx4){0.f, 0.f, 0.f, 0.f};
      accL[i][j] = (floatx4){0.f, 0.f, 0.f, 0.f};
    }

  const int rstage = tid >> 2;
  const int cstage = (tid & 3) * 8;
  const long aoff = (tm + rstage) * (long)K + cstage;
  const long boff = (tn + rstage) * (long)K + cstage;
  const unsigned short* Asrc[3] = {Ah + aoff, Am + aoff, Al + aoff};
  const unsigned short* Bsrc[3] = {Bh + boff, Bm + boff, Bl + boff};

  for (int k0 = kbase; k0 < kbase + ksize; k0 += 32) {
#pragma unroll
    for (int p = 0; p < 3; p++) {
      __builtin_amdgcn_global_load_lds(
          (const __attribute__((address_space(1))) void*)(Asrc[p] + k0),
          (__attribute__((address_space(3))) void*)(sA[p] + wave * 512), 16, 0, 0);
      __builtin_amdgcn_global_load_lds(
          (const __attribute__((address_space(1))) void*)(Bsrc[p] + k0),
          (__attribute__((address_space(3))) void*)(sB[p] + wave * 512), 16, 0, 0);
    }
    __syncthreads();

    const int fr = lane & 15;
    const int koff = (lane >> 4) * 8;
    short8 a_[3][2], b_[3][2];
#pragma unroll
    for (int p = 0; p < 3; p++)
#pragma unroll
      for (int mf = 0; mf < 2; mf++) {
        a_[p][mf] = *(const short8*)(sA[p] + (wm + mf * 16 + fr) * 32 + koff);
        b_[p][mf] = *(const short8*)(sB[p] + (wn + mf * 16 + fr) * 32 + koff);
      }
#pragma unroll
    for (int mf = 0; mf < 2; mf++)
#pragma unroll
      for (int nf = 0; nf < 2; nf++) {
        accH[mf][nf] = __builtin_amdgcn_mfma_f32_16x16x32_bf16(
            a_[0][mf], b_[0][nf], accH[mf][nf], 0, 0, 0);  // hh
        accL[mf][nf] = __builtin_amdgcn_mfma_f32_16x16x32_bf16(
            a_[0][mf], b_[1][nf], accL[mf][nf], 0, 0, 0);  // hm
        accL[mf][nf] = __builtin_amdgcn_mfma_f32_16x16x32_bf16(
            a_[1][mf], b_[0][nf], accL[mf][nf], 0, 0, 0);  // mh
        accL[mf][nf] = __builtin_amdgcn_mfma_f32_16x16x32_bf16(
            a_[0][mf], b_[2][nf], accL[mf][nf], 0, 0, 0);  // hl
        accL[mf][nf] = __builtin_amdgcn_mfma_f32_16x16x32_bf16(
            a_[2][mf], b_[0][nf], accL[mf][nf], 0, 0, 0);  // lh
        accL[mf][nf] = __builtin_amdgcn_mfma_f32_16x16x32_bf16(
            a_[1][mf], b_[1][nf], accL[mf][nf], 0, 0, 0);  // mm
      }
    __syncthreads();
  }

  const long crow = tm + wm + ((lane >> 4) * 4);
  const long ccol = tn + wn + (lane & 15);
#pragma unroll
  for (int mf = 0; mf < 2; mf++)
#pragma unroll
    for (int nf = 0; nf < 2; nf++)
#pragma unroll
      for (int r = 0; r < 4; r++)
        C[(crow + mf * 16 + r) * (long)N + ccol + nf * 16] =
            accH[mf][nf][r] + accL[mf][nf][r];
}

// ------- bias + reduce split-K partials + L2-normalize -> bf16 + f32 -------
__global__ __launch_bounds__(256) void norm_bias_rows(
    const float* __restrict__ P0, const float* __restrict__ P1,
    const float* __restrict__ P2, const float* __restrict__ P3, int nparts,
    const float* __restrict__ bias, unsigned short* __restrict__ Pn,
    float* __restrict__ Pn32) {
  const int b = blockIdx.x, tid = threadIdx.x;
  float4 v = ((const float4*)(P0 + (long)b * 1024))[tid];
  if (nparts == 4) {
    float4 v1 = ((const float4*)(P1 + (long)b * 1024))[tid];
    float4 v2 = ((const float4*)(P2 + (long)b * 1024))[tid];
    float4 v3 = ((const float4*)(P3 + (long)b * 1024))[tid];
    v.x += v1.x + v2.x + v3.x; v.y += v1.y + v2.y + v3.y;
    v.z += v1.z + v2.z + v3.z; v.w += v1.w + v2.w + v3.w;
  }
  float4 bb = ((const float4*)bias)[tid];
  v.x += bb.x; v.y += bb.y; v.z += bb.z; v.w += bb.w;
  float ss = v.x * v.x + v.y * v.y + v.z * v.z + v.w * v.w;
#pragma unroll
  for (int off = 32; off > 0; off >>= 1) ss += __shfl_down(ss, off);
  __shared__ float wred[4];
  if ((tid & 63) == 0) wred[tid >> 6] = ss;
  __syncthreads();
  float tot = wred[0] + wred[1] + wred[2] + wred[3];
  float inv = 1.0f / fmaxf(sqrtf(tot), 1e-12f);
  float4 p = make_float4(v.x * inv, v.y * inv, v.z * inv, v.w * inv);
  ((float4*)Pn32)[b * 256 + tid] = p;
  ushort4 o;
  o.x = f2bf(p.x); o.y = f2bf(p.y); o.z = f2bf(p.z); o.w = f2bf(p.w);
  ((ushort4*)Pn)[b * 256 + tid] = o;
}

// ------- softmax from LDS-staged bf16 sims + exact argmax (f64 refine) -----
// Row's bf16 sims live in the BACK HALF of its f32 output row. Stage 64 KB
// to LDS once; pass A (max+sum) and pass B (exp+write+candidates) both read
// LDS; full f32 row then overwritten. One HBM read (L3-hot) + one write.
__global__ __launch_bounds__(256) void softmax_argmax_bf16(
    float* __restrict__ out, const float* __restrict__ Pn32,
    const float* __restrict__ protos, float* __restrict__ idx_out) {
  const int b = blockIdx.x, tid = threadIdx.x;
  const int wave = tid >> 6, lane = tid & 63;
  __shared__ unsigned short srw[32768];   // 64 KiB bf16 sims
  __shared__ float sm_[4], sl_[4];
  __shared__ int cand[64];
  __shared__ int ncand;

  const float4* src4 =
      (const float4*)((const char*)out + (size_t)b * 131072 + 65536);
  float4* lds4 = (float4*)srw;
#pragma unroll
  for (int j = 0; j < 16; j++) lds4[tid + 256 * j] = src4[tid + 256 * j];
  if (tid == 0) ncand = 0;
  __syncthreads();

  // pass A: online max/sum over this thread's 128 values (z = 10*sim)
  float m = -3.4e38f, l = 0.f;
#pragma unroll 4
  for (int j = 0; j < 16; j++) {
    short8 v = ((const short8*)srw)[tid + 256 * j];
    float z0 = bf2f((unsigned short)v[0]) * 10.f;
    float z1 = bf2f((unsigned short)v[1]) * 10.f;
    float z2 = bf2f((unsigned short)v[2]) * 10.f;
    float z3 = bf2f((unsigned short)v[3]) * 10.f;
    float z4 = bf2f((unsigned short)v[4]) * 10.f;
    float z5 = bf2f((unsigned short)v[5]) * 10.f;
    float z6 = bf2f((unsigned short)v[6]) * 10.f;
    float z7 = bf2f((unsigned short)v[7]) * 10.f;
    float m8 = fmaxf(fmaxf(fmaxf(z0, z1), fmaxf(z2, z3)),
                     fmaxf(fmaxf(z4, z5), fmaxf(z6, z7)));
    float nm = fmaxf(m, m8);
    float s = __expf(z0 - nm) + __expf(z1 - nm) + __expf(z2 - nm) +
              __expf(z3 - nm) + __expf(z4 - nm) + __expf(z5 - nm) +
              __expf(z6 - nm) + __expf(z7 - nm);
    l = l * __expf(m - nm) + s;
    m = nm;
  }
#pragma unroll
  for (int off = 1; off < 64; off <<= 1) {
    float mo = __shfl_xor(m, off);
    float lo = __shfl_xor(l, off);
    float nm = fmaxf(m, mo);
    l = l * __expf(m - nm) + lo * __expf(mo - nm);
    m = nm;
  }
  if (lane == 0) { sm_[wave] = m; sl_[wave] = l; }
  __syncthreads();
  const float Mz = fmaxf(fmaxf(sm_[0], sm_[1]), fmaxf(sm_[2], sm_[3]));
  const float L = sl_[0] * __expf(sm_[0] - Mz) + sl_[1] * __expf(sm_[1] - Mz) +
                  sl_[2] * __expf(sm_[2] - Mz) + sl_[3] * __expf(sm_[3] - Mz);
  const float invL = 1.0f / L;
  // margin: bf16 GEMM sim err <=0.004 + bf16 storage err <=0.0012; use 0.016
  const float thr = Mz * 0.1f - 0.016f;  // sim units

  // pass B: activations + candidate collection (all from LDS)
  float* orow = out + (long)b * 32768;
#pragma unroll 2
  for (int j = 0; j < 16; j++) {
    const int i8 = tid + 256 * j;
    short8 v = ((const short8*)srw)[i8];
    float s0 = bf2f((unsigned short)v[0]);
    float s1 = bf2f((unsigned short)v[1]);
    float s2 = bf2f((unsigned short)v[2]);
    float s3 = bf2f((unsigned short)v[3]);
    float s4 = bf2f((unsigned short)v[4]);
    float s5 = bf2f((unsigned short)v[5]);
    float s6 = bf2f((unsigned short)v[6]);
    float s7 = bf2f((unsigned short)v[7]);
    float mx = fmaxf(fmaxf(fmaxf(s0, s1), fmaxf(s2, s3)),
                     fmaxf(fmaxf(s4, s5), fmaxf(s6, s7)));
    if (mx >= thr) {
      if (s0 >= thr) { int p = atomicAdd(&ncand, 1); if (p < 64) cand[p] = i8 * 8 + 0; }
      if (s1 >= thr) { int p = atomicAdd(&ncand, 1); if (p < 64) cand[p] = i8 * 8 + 1; }
      if (s2 >= thr) { int p = atomicAdd(&ncand, 1); if (p < 64) cand[p] = i8 * 8 + 2; }
      if (s3 >= thr) { int p = atomicAdd(&ncand, 1); if (p < 64) cand[p] = i8 * 8 + 3; }
      if (s4 >= thr) { int p = atomicAdd(&ncand, 1); if (p < 64) cand[p] = i8 * 8 + 4; }
      if (s5 >= thr) { int p = atomicAdd(&ncand, 1); if (p < 64) cand[p] = i8 * 8 + 5; }
      if (s6 >= thr) { int p = atomicAdd(&ncand, 1); if (p < 64) cand[p] = i8 * 8 + 6; }
      if (s7 >= thr) { int p = atomicAdd(&ncand, 1); if (p < 64) cand[p] = i8 * 8 + 7; }
    }
    float4 e0, e1;
    e0.x = __expf(s0 * 10.f - Mz) * invL;
    e0.y = __expf(s1 * 10.f - Mz) * invL;
    e0.z = __expf(s2 * 10.f - Mz) * invL;
    e0.w = __expf(s3 * 10.f - Mz) * invL;
    e1.x = __expf(s4 * 10.f - Mz) * invL;
    e1.y = __expf(s5 * 10.f - Mz) * invL;
    e1.z = __expf(s6 * 10.f - Mz) * invL;
    e1.w = __expf(s7 * 10.f - Mz) * invL;
    ((float4*)orow)[2 * i8] = e0;
    ((float4*)orow)[2 * i8 + 1] = e1;
  }
  __syncthreads();
  int n = ncand < 64 ? ncand : 64;

  float4 pv = ((const float4*)(Pn32 + (long)b * 1024))[tid];
  __shared__ double dred[4];
  double best = -1e300;
  int besti = 0x7fffffff;
  for (int c = 0; c < n; c++) {
    int k = cand[c];
    float4 kv = ((const float4*)(protos + (long)k * 1024))[tid];
    double d = (double)pv.x * kv.x + (double)pv.y * kv.y +
               (double)pv.z * kv.z + (double)pv.w * kv.w;
#pragma unroll
    for (int off = 32; off > 0; off >>= 1) d += __shfl_down(d, off);
    if (lane == 0) dred[wave] = d;
    __syncthreads();
    if (tid == 0) {
      double tot = dred[0] + dred[1] + dred[2] + dred[3];
      if (tot > best || (tot == best && k < besti)) { best = tot; besti = k; }
    }
    __syncthreads();
  }
  if (tid == 0) idx_out[b] = (float)besti;
}

extern "C" void kernel_launch(void* const* d_in, const int* in_sizes, int n_in,
                              void* d_out, int out_size, void* d_ws, size_t ws_size,
                              hipStream_t stream) {
  const float* features = (const float*)d_in[0];
  const float* W        = (const float*)d_in[1];
  const float* bias     = (const float*)d_in[2];
  const float* protos   = (const float*)d_in[3];

  const size_t MB = 1024 * 1024;
  char* ws = (char*)d_ws;
  unsigned short* protoB = (unsigned short*)ws;              // 64 MiB
  unsigned short* Fh = (unsigned short*)(ws + 64 * MB);      // 2 MiB each
  unsigned short* Fm = (unsigned short*)(ws + 66 * MB);
  unsigned short* Fl = (unsigned short*)(ws + 68 * MB);
  unsigned short* Wh = (unsigned short*)(ws + 70 * MB);
  unsigned short* Wm = (unsigned short*)(ws + 72 * MB);
  unsigned short* Wl = (unsigned short*)(ws + 74 * MB);
  float*          P0 = (float*)(ws + 76 * MB);               // 4 MiB
  float*          P1 = (float*)(ws + 80 * MB);               // 4 MiB
  // Partials 2,3 use d_out as scratch (dead until gemm_nt overwrites it,
  // and norm_bias_rows consumes them before that in stream order).
  float*          P2 = (float*)d_out;
  float*          P3 = (float*)((char*)d_out + 4 * MB);
  // F/W splits dead after projection GEMM -> reuse their space:
  unsigned short* Pn   = (unsigned short*)(ws + 64 * MB);    // 2 MiB
  float*          Pn32 = (float*)(ws + 66 * MB);             // 4 MiB

  // split-K=4 needs 84 MiB of ws (P0/P1) + d_out scratch; graph-safe since
  // ws_size is constant across calls.
  const int ksplit = (ws_size >= 84 * MB) ? 4 : 1;

  float* S = (float*)d_out;                      // [1024,32768] f32 out
  float* idx_out = S + (size_t)1024 * 32768;     // [1024] float-coded

  prep_convert<<<18432, 256, 0, stream>>>(protos, protoB, features, Fh, Fm, Fl,
                                          W, Wh, Wm, Wl);
  gemm_split6_nt<<<dim3(16, 16, ksplit), 256, 0, stream>>>(
      Fh, Fm, Fl, Wh, Wm, Wl, P0, P2, 1024, 1024, 1024);
  norm_bias_rows<<<1024, 256, 0, stream>>>(P0, P1, P2, P3, ksplit, bias, Pn,
                                           Pn32);
  gemm_nt_bf16_256<<<512, 512, 0, stream>>>(Pn, protoB, (unsigned short*)d_out,
                                            1024, 32768, 1024);
  softmax_argmax_bf16<<<1024, 256, 0, stream>>>(S, Pn32, protos, idx_out);
}